// Round 1
// 560.757 us; speedup vs baseline: 1.0177x; 1.0177x over previous
//
#include <hip/hip_runtime.h>
#include <hip/hip_bf16.h>

// Problem constants
#define B_    64
#define T_    1000
#define IN_   257
#define HID_  40
#define G3_   120
#define OUT_  257
#define M_    (B_*T_)   // 64000
#define NGI_  480
#define KP_   736       // padded KAN feature dim (720 real) = 92 groups of 8
#define KP1_  288       // padded GEMM1 K (257 real)
#define NP_   272       // padded OUT_ for k3

// ws layout:
// gi0 240x64000 bf16 (layer0 gates, col-major; fwd 0..119 | bwd 120..239) = 30,720,000
// gi1 240x64000 bf16 (layer1 gates, col-major; fwd 0..119 | bwd 120..239) = 30,720,000
// P   column-block-major: [92 groups][64000 rows][8 bf16]                 = 94,208,000
// Wk  272x736  bf16  =    400,384
// Wb  480x288  bf16  =    276,480
#define OFF_GI1 30720000ull
#define OFF_P   61440000ull
#define OFF_WK  (OFF_P + 94208000ull)
#define OFF_WB  (OFF_WK + 400384ull)

typedef __attribute__((ext_vector_type(8))) short bfx8;   // 8 bf16 = 4 VGPR
typedef __attribute__((ext_vector_type(4))) short bfx4;   // 8 B
typedef __attribute__((ext_vector_type(4))) float f32x4;  // MFMA C/D

__device__ __forceinline__ float sigf(float x){ return 1.0f/(1.0f + __expf(-x)); }
__device__ __forceinline__ float tanhfast(float x){ return 1.0f - 2.0f/(__expf(2.0f*x)+1.0f); }
__device__ __forceinline__ float gridp(int p){ return (float)(p-3)*0.4f - 1.0f; }

__device__ __forceinline__ void bspline8(float x, float* o){
    float b[11];
#pragma unroll
    for (int p=0;p<11;p++) b[p] = (x >= gridp(p) && x < gridp(p+1)) ? 1.0f : 0.0f;
#pragma unroll
    for (int k=1;k<=3;k++){
#pragma unroll
        for (int j=0;j<=10-k;j++){
            float gj=gridp(j), gjk=gridp(j+k), gjk1=gridp(j+k+1), gj1=gridp(j+1);
            b[j] = (x-gj)/(gjk-gj)*b[j] + (gjk1-x)/(gjk1-gj1)*b[j+1];
        }
    }
#pragma unroll
    for (int m=0;m<8;m++) o[m]=b[m];
}

__device__ __forceinline__ short bfbits(float v){
    __hip_bfloat16 h = __float2bfloat16(v);
    return *(short*)&h;
}
__device__ __forceinline__ float b2f(short s){
    return __uint_as_float(((unsigned)(unsigned short)s) << 16);
}

// Pack Wk[272][736] bf16 (logical-k row-major; matches P's logical column order)
__global__ __launch_bounds__(256) void kprep(const float* __restrict__ bw,
                                             const float* __restrict__ sw,
                                             const float* __restrict__ ss,
                                             __hip_bfloat16* __restrict__ wk){
    int idx = blockIdx.x*256 + threadIdx.x;
    if (idx >= NP_*(KP_/8)) return;
    int o = idx / (KP_/8), q = idx % (KP_/8);
    bfx8 pk;
#pragma unroll
    for (int e=0;e<8;e++){
        int k = q*8 + e;
        float v = 0.0f;
        if (o < OUT_ && k < 720){
            if (k < 80) v = bw[o*80 + k];
            else { int i = (k-80)>>3, m = (k-80)&7; v = sw[(o*80+i)*8 + m] * ss[o*80+i]; }
        }
        pk[e] = bfbits(v);
    }
    *(bfx8*)((void*)&wk[(size_t)o*KP_ + q*8]) = pk;
}

// Pack Wb[480][288] bf16 from Wih_f | Wih_b
__global__ __launch_bounds__(256) void wprep(const float* __restrict__ Wf,
                                             const float* __restrict__ Wbk,
                                             __hip_bfloat16* __restrict__ wb){
    int idx = blockIdx.x*256 + threadIdx.x;
    if (idx >= NGI_*(KP1_/8)) return;
    int n = idx / (KP1_/8), q = idx % (KP1_/8);
    bfx8 pk;
#pragma unroll
    for (int e=0;e<8;e++){
        int k = q*8 + e;
        float v = 0.0f;
        if (k < IN_) v = (n < 240) ? Wf[(size_t)n*IN_ + k] : Wbk[(size_t)(n-240)*IN_ + k];
        pk[e] = bfbits(v);
    }
    *(bfx8*)((void*)&wb[(size_t)n*KP1_ + q*8]) = pk;
}

// GEMM1 (MFMA): layer0 gates -> gi0[gate][m] col-major, layer1 gates -> gi1[gate][m] col-major
__global__ __launch_bounds__(256) void k1_gemm(const float* __restrict__ X,
                                               const __hip_bfloat16* __restrict__ Wb16,
                                               const float* __restrict__ bf,
                                               const float* __restrict__ bb,
                                               __hip_bfloat16* __restrict__ gi0,
                                               __hip_bfloat16* __restrict__ gi1){
    __shared__ __hip_bfloat16 Asm[128*40];
    __shared__ __hip_bfloat16 Bsm[160*40];
    int tid = threadIdx.x, wave = tid>>6, lane = tid&63;
    int m0 = blockIdx.y*128, n0 = blockIdx.x*160;
    f32x4 acc[2][10];
#pragma unroll
    for (int s=0;s<2;s++)
#pragma unroll
        for (int j=0;j<10;j++) acc[s][j] = (f32x4){0.f,0.f,0.f,0.f};

    for (int k0=0;k0<KP1_;k0+=32){
#pragma unroll
        for (int p=0;p<2;p++){
            int c = tid + p*256;
            int row = c>>2, kc = (c&3)*8;
            bfx8 pk;
#pragma unroll
            for (int e=0;e<8;e++){
                int k = k0 + kc + e;
                float v = (k < IN_) ? X[(size_t)(m0+row)*IN_ + k] : 0.0f;
                pk[e] = bfbits(v);
            }
            *(bfx8*)((void*)&Asm[row*40 + kc]) = pk;
        }
#pragma unroll
        for (int p=0;p<3;p++){
            int c = tid + p*256;
            if (c < 640){
                int row = c>>2, kc = (c&3)*8;
                *(bfx8*)((void*)&Bsm[row*40 + kc]) =
                    *(const bfx8*)&Wb16[(size_t)(n0+row)*KP1_ + k0 + kc];
            }
        }
        __syncthreads();
        int kf = (lane>>4)*8, rl = lane&15;
        bfx8 a0 = *(bfx8*)((void*)&Asm[(wave*32 + rl)*40 + kf]);
        bfx8 a1 = *(bfx8*)((void*)&Asm[(wave*32 + 16 + rl)*40 + kf]);
#pragma unroll
        for (int j=0;j<10;j++){
            bfx8 b = *(bfx8*)((void*)&Bsm[(j*16 + rl)*40 + kf]);
            acc[0][j] = __builtin_amdgcn_mfma_f32_16x16x32_bf16(a0, b, acc[0][j], 0,0,0);
            acc[1][j] = __builtin_amdgcn_mfma_f32_16x16x32_bf16(a1, b, acc[1][j], 0,0,0);
        }
        __syncthreads();
    }
    int rl = lane&15, quad = lane>>4;
#pragma unroll
    for (int j=0;j<10;j++){
        int n = n0 + j*16 + rl;
        float bias = (n < 240) ? bf[n] : bb[n-240];
        int d  = (n >= 240) ? 1 : 0;
        int nn = n - 240*d;
#pragma unroll
        for (int s=0;s<2;s++){
            int mb = m0 + wave*32 + s*16 + quad*4;
            bfx4 v;
#pragma unroll
            for (int r=0;r<4;r++) v[r] = bfbits(acc[s][j][r] + bias);
            if (nn < 120){            // layer0 gate -> gi0 col-major (8B vector store)
                *(bfx4*)((void*)&gi0[(size_t)(d*120 + nn)*M_ + mb]) = v;
            } else {                  // layer1 gate -> gi1 col-major (8B vector store)
                *(bfx4*)((void*)&gi1[(size_t)(d*120 + nn - 120)*M_ + mb]) = v;
            }
        }
    }
}

// Pointwise GRU + feature build -> P (column-block-major [92][M][8] bf16).
// 320-thr blocks = 5 waves; wave w owns feature group j = w*8..w*8+7 for the
// block's 64 rows (lane = row). Layer-0 h0 computed cooperatively into LDS.
// All gi0/gi1 reads and all P writes are coalesced; 10000 waves total.
__global__ __launch_bounds__(320, 4) void k2_gru(const __hip_bfloat16* __restrict__ gi0,
                                             const __hip_bfloat16* __restrict__ gi1,
                                             const float* __restrict__ Whh_f,
                                             const float* __restrict__ bhh_f,
                                             const float* __restrict__ Whh_b,
                                             const float* __restrict__ bhh_b,
                                             __hip_bfloat16* __restrict__ P){
    __shared__ float h0_lds[HID_][64];
    int tid = threadIdx.x;
    int wave = __builtin_amdgcn_readfirstlane(tid>>6);  // 0..4, wave-uniform
    int lane = tid & 63;
    int dir = (blockIdx.x >= 1000) ? 1 : 0;
    int m = (blockIdx.x - dir*1000)*64 + lane;          // output row
    int b = m / T_, t = m % T_;
    int src = dir ? (b*T_ + (T_-1-t)) : m;              // gate-source row
    const float* Whh1  = (dir ? Whh_b : Whh_f) + G3_*HID_;
    const float* bhh0v = dir ? bhh_b : bhh_f;
    const float* bhh1  = bhh0v + G3_;

    // ---- layer 0: wave w computes h0[w*8..w*8+7] for its lane's row ----
    const __hip_bfloat16* g0 = gi0 + (size_t)(dir*120)*M_ + src;
    float h0own[8];
#pragma unroll
    for (int jj=0;jj<8;jj++){
        int j = wave*8 + jj;
        float ir = b2f(*(const short*)&g0[(size_t)j*M_]);
        float iz = b2f(*(const short*)&g0[(size_t)(40+j)*M_]);
        float in = b2f(*(const short*)&g0[(size_t)(80+j)*M_]);
        float r = sigf(ir + bhh0v[j]);
        float z = sigf(iz + bhh0v[40+j]);
        float n = tanhfast(in + r*bhh0v[80+j]);
        float h0 = (1.0f - z)*n;
        h0own[jj] = h0;
        h0_lds[j][lane] = h0;
    }
    __syncthreads();

    // ---- layer 1: 8 features per thread; Whh1 indices wave-uniform -> s_loads ----
    const __hip_bfloat16* g1 = gi1 + (size_t)(dir*120)*M_ + src;
    bfx8 sil;
#pragma unroll
    for (int jj=0;jj<8;jj++){
        int j = wave*8 + jj;
        float gr = bhh1[j], gz = bhh1[40+j], gn = bhh1[80+j];
#pragma unroll
        for (int k=0;k<HID_;k++){
            float h = h0_lds[k][lane];
            gr += Whh1[j*HID_+k]      * h;
            gz += Whh1[(40+j)*HID_+k] * h;
            gn += Whh1[(80+j)*HID_+k] * h;
        }
        float ir = b2f(*(const short*)&g1[(size_t)j*M_]);
        float iz = b2f(*(const short*)&g1[(size_t)(40+j)*M_]);
        float in = b2f(*(const short*)&g1[(size_t)(80+j)*M_]);
        float r = sigf(ir + gr);
        float z = sigf(iz + gz);
        float n = tanhfast(in + r*gn);
        float h1 = (1.0f - z)*n + z*h0own[jj];
        sil[jj] = bfbits(h1 * sigf(h1));
        float bb8[8];
        bspline8(h1, bb8);
        bfx8 pk;
#pragma unroll
        for (int mm=0;mm<8;mm++) pk[mm] = bfbits(bb8[mm]);
        // bspline features: logical cols 80+(dir*40+j)*8 .. +7 -> group 10+dir*40+j
        *(bfx8*)((void*)&P[((size_t)(10 + dir*40 + j)*M_ + m)*8]) = pk;
    }
    // silu features: logical cols dir*40+wave*8 .. +7 -> group dir*5+wave
    *(bfx8*)((void*)&P[((size_t)(dir*5 + wave)*M_ + m)*8]) = sil;
    if (dir && wave==0){   // zero K-pad groups 90,91 (logical cols 720..735)
        bfx8 z8 = {0,0,0,0,0,0,0,0};
        *(bfx8*)((void*)&P[((size_t)90*M_ + m)*8]) = z8;
        *(bfx8*)((void*)&P[((size_t)91*M_ + m)*8]) = z8;
    }
}

// GEMM2 (MFMA): out[m,o] = 1.2*sigmoid(slope[o]*sum_k P[m,k]*Wk[o,k])
// A (P) is column-block-major [92][M][8]; staging loads are coalesced 16B runs.
__global__ __launch_bounds__(256) void k3_gemm(const __hip_bfloat16* __restrict__ P,
                                               const __hip_bfloat16* __restrict__ Wk,
                                               const float* __restrict__ slope,
                                               float* __restrict__ outp){
    __shared__ __hip_bfloat16 Asm[128*40];
    __shared__ __hip_bfloat16 Bsm[NP_*40];
    int tid = threadIdx.x, wave = tid>>6, lane = tid&63;
    int m0 = blockIdx.x*128;
    f32x4 acc[2][17];
#pragma unroll
    for (int s=0;s<2;s++)
#pragma unroll
        for (int j=0;j<17;j++) acc[s][j] = (f32x4){0.f,0.f,0.f,0.f};

    for (int k0=0;k0<KP_;k0+=32){
#pragma unroll
        for (int p=0;p<2;p++){
            int c = tid + p*256;
            int row = c>>2, q = c&3;
            *(bfx8*)((void*)&Asm[row*40 + q*8]) =
                *(const bfx8*)&P[((size_t)(k0/8 + q)*M_ + m0 + row)*8];
        }
#pragma unroll
        for (int p=0;p<5;p++){
            int c = tid + p*256;
            if (c < NP_*4){
                int row = c>>2, kc = (c&3)*8;
                *(bfx8*)((void*)&Bsm[row*40 + kc]) =
                    *(const bfx8*)&Wk[(size_t)row*KP_ + k0 + kc];
            }
        }
        __syncthreads();
        int kf = (lane>>4)*8, rl = lane&15;
        bfx8 a0 = *(bfx8*)((void*)&Asm[(wave*32 + rl)*40 + kf]);
        bfx8 a1 = *(bfx8*)((void*)&Asm[(wave*32 + 16 + rl)*40 + kf]);
#pragma unroll
        for (int j=0;j<17;j++){
            bfx8 b = *(bfx8*)((void*)&Bsm[(j*16 + rl)*40 + kf]);
            acc[0][j] = __builtin_amdgcn_mfma_f32_16x16x32_bf16(a0, b, acc[0][j], 0,0,0);
            acc[1][j] = __builtin_amdgcn_mfma_f32_16x16x32_bf16(a1, b, acc[1][j], 0,0,0);
        }
        __syncthreads();
    }
    int rl = lane&15, quad = lane>>4;
#pragma unroll
    for (int j=0;j<17;j++){
        int n = j*16 + rl;
        if (n < OUT_){
            float sl = slope[n];
#pragma unroll
            for (int s=0;s<2;s++){
                int mb = m0 + wave*32 + s*16 + quad*4;
#pragma unroll
                for (int r=0;r<4;r++)
                    outp[(size_t)(mb+r)*OUT_ + n] = 1.2f * sigf(sl*acc[s][j][r]);
            }
        }
    }
}

extern "C" void kernel_launch(void* const* d_in, const int* in_sizes, int n_in,
                              void* d_out, int out_size, void* d_ws, size_t ws_size,
                              hipStream_t stream) {
    const float* x      = (const float*)d_in[0];
    const float* Wih_f  = (const float*)d_in[1];
    const float* Whh_f  = (const float*)d_in[2];
    const float* bih_f  = (const float*)d_in[3];
    const float* bhh_f  = (const float*)d_in[4];
    const float* Wih_b  = (const float*)d_in[5];
    const float* Whh_b  = (const float*)d_in[6];
    const float* bih_b  = (const float*)d_in[7];
    const float* bhh_b  = (const float*)d_in[8];
    const float* base_w = (const float*)d_in[9];
    const float* spl_w  = (const float*)d_in[10];
    const float* spl_s  = (const float*)d_in[11];
    const float* slope  = (const float*)d_in[12];

    char* ws = (char*)d_ws;
    __hip_bfloat16* gi0 = (__hip_bfloat16*)ws;
    __hip_bfloat16* gi1 = (__hip_bfloat16*)(ws + OFF_GI1);
    __hip_bfloat16* P   = (__hip_bfloat16*)(ws + OFF_P);
    __hip_bfloat16* Wk  = (__hip_bfloat16*)(ws + OFF_WK);
    __hip_bfloat16* Wb  = (__hip_bfloat16*)(ws + OFF_WB);
    float* outp = (float*)d_out;

    hipLaunchKernelGGL(kprep, dim3((NP_*(KP_/8) + 255)/256), dim3(256), 0, stream,
                       base_w, spl_w, spl_s, Wk);
    hipLaunchKernelGGL(wprep, dim3((NGI_*(KP1_/8) + 255)/256), dim3(256), 0, stream,
                       Wih_f, Wih_b, Wb);
    hipLaunchKernelGGL(k1_gemm, dim3(3, 500), dim3(256), 0, stream,
                       x, Wb, bih_f, bih_b, gi0, gi1);
    hipLaunchKernelGGL(k2_gru, dim3(2000), dim3(320), 0, stream,
                       gi0, gi1, Whh_f, bhh_f, Whh_b, bhh_b, P);
    hipLaunchKernelGGL(k3_gemm, dim3(500), dim3(256), 0, stream,
                       P, Wk, slope, outp);
}

// Round 2
// 478.630 us; speedup vs baseline: 1.1924x; 1.1716x over previous
//
#include <hip/hip_runtime.h>
#include <hip/hip_bf16.h>

// Problem constants
#define B_    64
#define T_    1000
#define IN_   257
#define HID_  40
#define G3_   120
#define OUT_  257
#define M_    (B_*T_)   // 64000
#define NGI_  480
#define KP_   736       // padded KAN feature dim (720 real) = 92 groups of 8
#define KP1_  288       // padded GEMM1 K (257 real)
#define NP_   272       // padded OUT_ for k3

// ws layout:
// gi0 240x64000 bf16 (layer0 gates, col-major; fwd 0..119 | bwd 120..239) = 30,720,000
// gi1 240x64000 bf16 (layer1 gates, col-major)                            = 30,720,000
// P   column-block-major: [92 groups][64000 rows][8 bf16]                 = 94,208,000
// Wk  272x736  bf16  =    400,384
// Wb  480x288  bf16  =    276,480
// h0T f32 [2 dir][40][64000]  = 20,480,000
// ghT f32 [2 dir][120][64000] = 61,440,000
#define OFF_GI1 30720000ull
#define OFF_P   61440000ull
#define OFF_WK  (OFF_P + 94208000ull)
#define OFF_WB  (OFF_WK + 400384ull)
#define OFF_H0  (OFF_WB + 276480ull)
#define OFF_GH  (OFF_H0 + 20480000ull)

typedef __attribute__((ext_vector_type(8))) short bfx8;   // 8 bf16 = 4 VGPR
typedef __attribute__((ext_vector_type(4))) short bfx4;   // 8 B
typedef __attribute__((ext_vector_type(4))) float f32x4;  // MFMA C/D

__device__ __forceinline__ float sigf(float x){ return 1.0f/(1.0f + __expf(-x)); }
__device__ __forceinline__ float tanhfast(float x){ return 1.0f - 2.0f/(__expf(2.0f*x)+1.0f); }

__device__ __forceinline__ short bfbits(float v){
    __hip_bfloat16 h = __float2bfloat16(v);
    return *(short*)&h;
}
__device__ __forceinline__ float b2f(short s){
    return __uint_as_float(((unsigned)(unsigned short)s) << 16);
}

// Pack Wk[272][736] bf16 (logical-k row-major; matches P's logical column order)
__global__ __launch_bounds__(256) void kprep(const float* __restrict__ bw,
                                             const float* __restrict__ sw,
                                             const float* __restrict__ ss,
                                             __hip_bfloat16* __restrict__ wk){
    int idx = blockIdx.x*256 + threadIdx.x;
    if (idx >= NP_*(KP_/8)) return;
    int o = idx / (KP_/8), q = idx % (KP_/8);
    bfx8 pk;
#pragma unroll
    for (int e=0;e<8;e++){
        int k = q*8 + e;
        float v = 0.0f;
        if (o < OUT_ && k < 720){
            if (k < 80) v = bw[o*80 + k];
            else { int i = (k-80)>>3, m = (k-80)&7; v = sw[(o*80+i)*8 + m] * ss[o*80+i]; }
        }
        pk[e] = bfbits(v);
    }
    *(bfx8*)((void*)&wk[(size_t)o*KP_ + q*8]) = pk;
}

// Pack Wb[480][288] bf16 from Wih_f | Wih_b
__global__ __launch_bounds__(256) void wprep(const float* __restrict__ Wf,
                                             const float* __restrict__ Wbk,
                                             __hip_bfloat16* __restrict__ wb){
    int idx = blockIdx.x*256 + threadIdx.x;
    if (idx >= NGI_*(KP1_/8)) return;
    int n = idx / (KP1_/8), q = idx % (KP1_/8);
    bfx8 pk;
#pragma unroll
    for (int e=0;e<8;e++){
        int k = q*8 + e;
        float v = 0.0f;
        if (k < IN_) v = (n < 240) ? Wf[(size_t)n*IN_ + k] : Wbk[(size_t)(n-240)*IN_ + k];
        pk[e] = bfbits(v);
    }
    *(bfx8*)((void*)&wb[(size_t)n*KP1_ + q*8]) = pk;
}

// GEMM1 (MFMA): layer0 gates -> gi0[gate][m] col-major, layer1 gates -> gi1[gate][m] col-major
__global__ __launch_bounds__(256) void k1_gemm(const float* __restrict__ X,
                                               const __hip_bfloat16* __restrict__ Wb16,
                                               const float* __restrict__ bf,
                                               const float* __restrict__ bb,
                                               __hip_bfloat16* __restrict__ gi0,
                                               __hip_bfloat16* __restrict__ gi1){
    __shared__ __hip_bfloat16 Asm[128*40];
    __shared__ __hip_bfloat16 Bsm[160*40];
    int tid = threadIdx.x, wave = tid>>6, lane = tid&63;
    int m0 = blockIdx.y*128, n0 = blockIdx.x*160;
    f32x4 acc[2][10];
#pragma unroll
    for (int s=0;s<2;s++)
#pragma unroll
        for (int j=0;j<10;j++) acc[s][j] = (f32x4){0.f,0.f,0.f,0.f};

    for (int k0=0;k0<KP1_;k0+=32){
#pragma unroll
        for (int p=0;p<2;p++){
            int c = tid + p*256;
            int row = c>>2, kc = (c&3)*8;
            int kg = k0 + kc;
            bfx8 pk;
            if (kg + 7 < IN_){          // vector path: 2x float4 (dword-aligned ok on gfx9+)
                const float* xp = &X[(size_t)(m0+row)*IN_ + kg];
                f32x4 x0 = *(const f32x4*)xp;
                f32x4 x1 = *(const f32x4*)(xp+4);
#pragma unroll
                for (int e=0;e<4;e++){ pk[e] = bfbits(x0[e]); pk[4+e] = bfbits(x1[e]); }
            } else {
#pragma unroll
                for (int e=0;e<8;e++){
                    int k = kg + e;
                    float v = (k < IN_) ? X[(size_t)(m0+row)*IN_ + k] : 0.0f;
                    pk[e] = bfbits(v);
                }
            }
            *(bfx8*)((void*)&Asm[row*40 + kc]) = pk;
        }
#pragma unroll
        for (int p=0;p<3;p++){
            int c = tid + p*256;
            if (c < 640){
                int row = c>>2, kc = (c&3)*8;
                *(bfx8*)((void*)&Bsm[row*40 + kc]) =
                    *(const bfx8*)&Wb16[(size_t)(n0+row)*KP1_ + k0 + kc];
            }
        }
        __syncthreads();
        int kf = (lane>>4)*8, rl = lane&15;
        bfx8 a0 = *(bfx8*)((void*)&Asm[(wave*32 + rl)*40 + kf]);
        bfx8 a1 = *(bfx8*)((void*)&Asm[(wave*32 + 16 + rl)*40 + kf]);
#pragma unroll
        for (int j=0;j<10;j++){
            bfx8 b = *(bfx8*)((void*)&Bsm[(j*16 + rl)*40 + kf]);
            acc[0][j] = __builtin_amdgcn_mfma_f32_16x16x32_bf16(a0, b, acc[0][j], 0,0,0);
            acc[1][j] = __builtin_amdgcn_mfma_f32_16x16x32_bf16(a1, b, acc[1][j], 0,0,0);
        }
        __syncthreads();
    }
    int rl = lane&15, quad = lane>>4;
#pragma unroll
    for (int j=0;j<10;j++){
        int n = n0 + j*16 + rl;
        float bias = (n < 240) ? bf[n] : bb[n-240];
        int d  = (n >= 240) ? 1 : 0;
        int nn = n - 240*d;
#pragma unroll
        for (int s=0;s<2;s++){
            int mb = m0 + wave*32 + s*16 + quad*4;
            bfx4 v;
#pragma unroll
            for (int r=0;r<4;r++) v[r] = bfbits(acc[s][j][r] + bias);
            if (nn < 120){            // layer0 gate -> gi0 col-major (8B vector store)
                *(bfx4*)((void*)&gi0[(size_t)(d*120 + nn)*M_ + mb]) = v;
            } else {                  // layer1 gate -> gi1 col-major (8B vector store)
                *(bfx4*)((void*)&gi1[(size_t)(d*120 + nn - 120)*M_ + mb]) = v;
            }
        }
    }
}

// k2a: thread = (m, dir). Layer-0 pointwise -> h0[40] in REGISTERS, then the
// 120x40 Whh1 matvec as pure register FMA (Whh via scalar cache). Writes
// h0T f32 col-major and ghT = bhh1 + Whh1@h0 f32 col-major. No LDS.
__global__ __launch_bounds__(256, 2) void k2a(const __hip_bfloat16* __restrict__ gi0,
                                              const float* __restrict__ Whh_f,
                                              const float* __restrict__ bhh_f,
                                              const float* __restrict__ Whh_b,
                                              const float* __restrict__ bhh_b,
                                              float* __restrict__ h0T,
                                              float* __restrict__ ghT){
    int gidx = blockIdx.x*256 + threadIdx.x;    // 0..127999; dir uniform per block
    int dir = (gidx >= M_) ? 1 : 0;
    int m = gidx - dir*M_;
    int b = m / T_, t = m - b*T_;
    int src = dir ? (b*T_ + (T_-1-t)) : m;
    const float* Whh1  = (dir ? Whh_b : Whh_f) + G3_*HID_;
    const float* bhh0v = dir ? bhh_b : bhh_f;
    const float* bhh1  = bhh0v + G3_;

    const __hip_bfloat16* g0 = gi0 + (size_t)(dir*120)*M_ + src;
    float* h0o = h0T + (size_t)(dir*40)*M_ + m;
    float h0[HID_];
#pragma unroll
    for (int j=0;j<HID_;j++){
        float ir = b2f(*(const short*)&g0[(size_t)j*M_]);
        float iz = b2f(*(const short*)&g0[(size_t)(40+j)*M_]);
        float in = b2f(*(const short*)&g0[(size_t)(80+j)*M_]);
        float r = sigf(ir + bhh0v[j]);
        float z = sigf(iz + bhh0v[40+j]);
        float n = tanhfast(in + r*bhh0v[80+j]);
        h0[j] = (1.0f - z)*n;
        h0o[(size_t)j*M_] = h0[j];
    }

    float* gh = ghT + (size_t)(dir*120)*M_ + m;
#pragma unroll 2
    for (int f=0;f<HID_;f++){
        float gr = bhh1[f], gz = bhh1[40+f], gn = bhh1[80+f];
#pragma unroll
        for (int k=0;k<HID_;k++){
            float h = h0[k];
            gr += Whh1[f*HID_+k]      * h;
            gz += Whh1[(40+f)*HID_+k] * h;
            gn += Whh1[(80+f)*HID_+k] * h;
        }
        gh[(size_t)f*M_]      = gr;
        gh[(size_t)(40+f)*M_] = gz;
        gh[(size_t)(80+f)*M_] = gn;
    }
}

// k2c: thread = (m, dir, 8-feature group). Pure streaming pointwise:
// GRU layer-1 gates from gi1+ghT, silu, closed-form uniform cubic B-spline,
// coalesced bfx8 stores into column-block-major P. No LDS, no matvec.
__global__ __launch_bounds__(256, 4) void k2c(const __hip_bfloat16* __restrict__ gi1,
                                              const float* __restrict__ ghT,
                                              const float* __restrict__ h0T,
                                              __hip_bfloat16* __restrict__ P){
    int tid = threadIdx.x;
    int bb = blockIdx.x;            // 0..2499
    int mblk = bb % 250;
    int rest = bb / 250;            // 0..9
    int dir = rest / 5, grp = rest % 5;
    int m = mblk*256 + tid;
    int b = m / T_, t = m - b*T_;
    int src = dir ? (b*T_ + (T_-1-t)) : m;

    const __hip_bfloat16* g1 = gi1 + (size_t)(dir*120)*M_ + src;
    const float* gh  = ghT + (size_t)(dir*120)*M_ + m;
    const float* h0v = h0T + (size_t)(dir*40)*M_ + m;

    bfx8 sil;
#pragma unroll
    for (int jj=0;jj<8;jj++){
        int j = grp*8 + jj;
        float ir = b2f(*(const short*)&g1[(size_t)j*M_]);
        float iz = b2f(*(const short*)&g1[(size_t)(40+j)*M_]);
        float in = b2f(*(const short*)&g1[(size_t)(80+j)*M_]);
        float gr = gh[(size_t)j*M_];
        float gz = gh[(size_t)(40+j)*M_];
        float gn = gh[(size_t)(80+j)*M_];
        float r = sigf(ir + gr);
        float z = sigf(iz + gz);
        float n = tanhfast(in + r*gn);
        float h1 = (1.0f - z)*n + z*h0v[(size_t)j*M_];
        sil[jj] = bfbits(h1 * sigf(h1));

        // closed-form uniform cubic B-spline: knots t_p=(p-3)*0.4-1, h=0.4
        float tt = (h1 + 1.0f) * 2.5f;
        float fs = floorf(tt);
        fs = fminf(fmaxf(fs, 0.0f), 4.0f);
        int sp = (int)fs;
        float u  = tt - fs;
        float um = 1.0f - u;
        float u2 = u*u, u3 = u2*u;
        float N0 = um*um*um * (1.0f/6.0f);
        float N1 = (3.0f*u3 - 6.0f*u2 + 4.0f) * (1.0f/6.0f);
        float N2 = (-3.0f*u3 + 3.0f*u2 + 3.0f*u + 1.0f) * (1.0f/6.0f);
        float N3 = u3 * (1.0f/6.0f);
        bfx8 pk;
#pragma unroll
        for (int i=0;i<8;i++){
            int d = i - sp;
            float v = (d==0)?N0 : (d==1)?N1 : (d==2)?N2 : (d==3)?N3 : 0.0f;
            pk[i] = bfbits(v);
        }
        *(bfx8*)((void*)&P[((size_t)(10 + dir*40 + j)*M_ + m)*8]) = pk;
    }
    *(bfx8*)((void*)&P[((size_t)(dir*5 + grp)*M_ + m)*8]) = sil;
    if (dir==0 && grp==0){   // zero K-pad groups 90,91 (logical cols 720..735)
        bfx8 z8 = {0,0,0,0,0,0,0,0};
        *(bfx8*)((void*)&P[((size_t)90*M_ + m)*8]) = z8;
        *(bfx8*)((void*)&P[((size_t)91*M_ + m)*8]) = z8;
    }
}

// GEMM2 (MFMA): out[m,o] = 1.2*sigmoid(slope[o]*sum_k P[m,k]*Wk[o,k])
// A (P) is column-block-major [92][M][8]; staging loads are coalesced 16B runs.
__global__ __launch_bounds__(256) void k3_gemm(const __hip_bfloat16* __restrict__ P,
                                               const __hip_bfloat16* __restrict__ Wk,
                                               const float* __restrict__ slope,
                                               float* __restrict__ outp){
    __shared__ __hip_bfloat16 Asm[128*40];
    __shared__ __hip_bfloat16 Bsm[NP_*40];
    int tid = threadIdx.x, wave = tid>>6, lane = tid&63;
    int m0 = blockIdx.x*128;
    f32x4 acc[2][17];
#pragma unroll
    for (int s=0;s<2;s++)
#pragma unroll
        for (int j=0;j<17;j++) acc[s][j] = (f32x4){0.f,0.f,0.f,0.f};

    for (int k0=0;k0<KP_;k0+=32){
#pragma unroll
        for (int p=0;p<2;p++){
            int c = tid + p*256;
            int row = c>>2, q = c&3;
            *(bfx8*)((void*)&Asm[row*40 + q*8]) =
                *(const bfx8*)&P[((size_t)(k0/8 + q)*M_ + m0 + row)*8];
        }
#pragma unroll
        for (int p=0;p<5;p++){
            int c = tid + p*256;
            if (c < NP_*4){
                int row = c>>2, kc = (c&3)*8;
                *(bfx8*)((void*)&Bsm[row*40 + kc]) =
                    *(const bfx8*)&Wk[(size_t)row*KP_ + k0 + kc];
            }
        }
        __syncthreads();
        int kf = (lane>>4)*8, rl = lane&15;
        bfx8 a0 = *(bfx8*)((void*)&Asm[(wave*32 + rl)*40 + kf]);
        bfx8 a1 = *(bfx8*)((void*)&Asm[(wave*32 + 16 + rl)*40 + kf]);
#pragma unroll
        for (int j=0;j<17;j++){
            bfx8 b = *(bfx8*)((void*)&Bsm[(j*16 + rl)*40 + kf]);
            acc[0][j] = __builtin_amdgcn_mfma_f32_16x16x32_bf16(a0, b, acc[0][j], 0,0,0);
            acc[1][j] = __builtin_amdgcn_mfma_f32_16x16x32_bf16(a1, b, acc[1][j], 0,0,0);
        }
        __syncthreads();
    }
    int rl = lane&15, quad = lane>>4;
#pragma unroll
    for (int j=0;j<17;j++){
        int n = j*16 + rl;
        if (n < OUT_){
            float sl = slope[n];
#pragma unroll
            for (int s=0;s<2;s++){
                int mb = m0 + wave*32 + s*16 + quad*4;
#pragma unroll
                for (int r=0;r<4;r++)
                    outp[(size_t)(mb+r)*OUT_ + n] = 1.2f * sigf(sl*acc[s][j][r]);
            }
        }
    }
}

extern "C" void kernel_launch(void* const* d_in, const int* in_sizes, int n_in,
                              void* d_out, int out_size, void* d_ws, size_t ws_size,
                              hipStream_t stream) {
    const float* x      = (const float*)d_in[0];
    const float* Wih_f  = (const float*)d_in[1];
    const float* Whh_f  = (const float*)d_in[2];
    const float* bih_f  = (const float*)d_in[3];
    const float* bhh_f  = (const float*)d_in[4];
    const float* Wih_b  = (const float*)d_in[5];
    const float* Whh_b  = (const float*)d_in[6];
    const float* bih_b  = (const float*)d_in[7];
    const float* bhh_b  = (const float*)d_in[8];
    const float* base_w = (const float*)d_in[9];
    const float* spl_w  = (const float*)d_in[10];
    const float* spl_s  = (const float*)d_in[11];
    const float* slope  = (const float*)d_in[12];

    char* ws = (char*)d_ws;
    __hip_bfloat16* gi0 = (__hip_bfloat16*)ws;
    __hip_bfloat16* gi1 = (__hip_bfloat16*)(ws + OFF_GI1);
    __hip_bfloat16* P   = (__hip_bfloat16*)(ws + OFF_P);
    __hip_bfloat16* Wk  = (__hip_bfloat16*)(ws + OFF_WK);
    __hip_bfloat16* Wb  = (__hip_bfloat16*)(ws + OFF_WB);
    float* h0T          = (float*)(ws + OFF_H0);
    float* ghT          = (float*)(ws + OFF_GH);
    float* outp = (float*)d_out;

    hipLaunchKernelGGL(kprep, dim3((NP_*(KP_/8) + 255)/256), dim3(256), 0, stream,
                       base_w, spl_w, spl_s, Wk);
    hipLaunchKernelGGL(wprep, dim3((NGI_*(KP1_/8) + 255)/256), dim3(256), 0, stream,
                       Wih_f, Wih_b, Wb);
    hipLaunchKernelGGL(k1_gemm, dim3(3, 500), dim3(256), 0, stream,
                       x, Wb, bih_f, bih_b, gi0, gi1);
    hipLaunchKernelGGL(k2a, dim3(500), dim3(256), 0, stream,
                       gi0, Whh_f, bhh_f, Whh_b, bhh_b, h0T, ghT);
    hipLaunchKernelGGL(k2c, dim3(2500), dim3(256), 0, stream,
                       gi1, ghT, h0T, P);
    hipLaunchKernelGGL(k3_gemm, dim3(500), dim3(256), 0, stream,
                       P, Wk, slope, outp);
}

// Round 3
// 393.936 us; speedup vs baseline: 1.4487x; 1.2150x over previous
//
#include <hip/hip_runtime.h>
#include <hip/hip_bf16.h>

// Problem constants
#define B_    64
#define T_    1000
#define IN_   257
#define HID_  40
#define G3_   120
#define OUT_  257
#define M_    (B_*T_)   // 64000
#define NGI_  480
#define KP_   736       // padded KAN feature dim (720 real) = 92 groups of 8
#define KP1_  288       // padded GEMM1 K (257 real)
#define NP_   288       // padded OUT_ for k3 (18x16 cols)

// ws layout:
// gi0 240x64000 bf16 (layer0 gates, col-major; fwd 0..119 | bwd 120..239) = 30,720,000
// gi1 240x64000 bf16 (layer1 gates, col-major)                            = 30,720,000
// P   column-block-major: [92 groups][64000 rows][8 bf16]                 = 94,208,000
// Wk  288x736  bf16  =    423,936
// Wb  480x288  bf16  =    276,480
// h0T f32 [2 dir][40][64000]  = 20,480,000
// ghT f32 [2 dir][120][64000] = 61,440,000
#define OFF_GI1 30720000ull
#define OFF_P   61440000ull
#define OFF_WK  (OFF_P + 94208000ull)
#define OFF_WB  (OFF_WK + 423936ull)
#define OFF_H0  (OFF_WB + 276480ull)
#define OFF_GH  (OFF_H0 + 20480000ull)

typedef __attribute__((ext_vector_type(8))) short bfx8;   // 8 bf16 = 4 VGPR
typedef __attribute__((ext_vector_type(4))) short bfx4;   // 8 B
typedef __attribute__((ext_vector_type(4))) float f32x4;  // MFMA C/D

__device__ __forceinline__ float sigf(float x){ return 1.0f/(1.0f + __expf(-x)); }
__device__ __forceinline__ float tanhfast(float x){ return 1.0f - 2.0f/(__expf(2.0f*x)+1.0f); }

__device__ __forceinline__ short bfbits(float v){
    __hip_bfloat16 h = __float2bfloat16(v);
    return *(short*)&h;
}
__device__ __forceinline__ float b2f(short s){
    return __uint_as_float(((unsigned)(unsigned short)s) << 16);
}

// Pack Wk[288][736] bf16 (rows 257..287 zero)
__global__ __launch_bounds__(256) void kprep(const float* __restrict__ bw,
                                             const float* __restrict__ sw,
                                             const float* __restrict__ ss,
                                             __hip_bfloat16* __restrict__ wk){
    int idx = blockIdx.x*256 + threadIdx.x;
    if (idx >= NP_*(KP_/8)) return;
    int o = idx / (KP_/8), q = idx % (KP_/8);
    bfx8 pk;
#pragma unroll
    for (int e=0;e<8;e++){
        int k = q*8 + e;
        float v = 0.0f;
        if (o < OUT_ && k < 720){
            if (k < 80) v = bw[o*80 + k];
            else { int i = (k-80)>>3, m = (k-80)&7; v = sw[(o*80+i)*8 + m] * ss[o*80+i]; }
        }
        pk[e] = bfbits(v);
    }
    *(bfx8*)((void*)&wk[(size_t)o*KP_ + q*8]) = pk;
}

// Pack Wb[480][288] bf16 from Wih_f | Wih_b
__global__ __launch_bounds__(256) void wprep(const float* __restrict__ Wf,
                                             const float* __restrict__ Wbk,
                                             __hip_bfloat16* __restrict__ wb){
    int idx = blockIdx.x*256 + threadIdx.x;
    if (idx >= NGI_*(KP1_/8)) return;
    int n = idx / (KP1_/8), q = idx % (KP1_/8);
    bfx8 pk;
#pragma unroll
    for (int e=0;e<8;e++){
        int k = q*8 + e;
        float v = 0.0f;
        if (k < IN_) v = (n < 240) ? Wf[(size_t)n*IN_ + k] : Wbk[(size_t)(n-240)*IN_ + k];
        pk[e] = bfbits(v);
    }
    *(bfx8*)((void*)&wb[(size_t)n*KP1_ + q*8]) = pk;
}

// GEMM1 (MFMA, pipelined dbuf): M-tile 256, N-tile 160, 8 waves (4x2).
// Per K-step: issue next-tile global loads -> compute -> ds_write -> 1 barrier.
__global__ __launch_bounds__(512) void k1_gemm(const float* __restrict__ X,
                                               const __hip_bfloat16* __restrict__ Wb16,
                                               const float* __restrict__ bf,
                                               const float* __restrict__ bb,
                                               __hip_bfloat16* __restrict__ gi0,
                                               __hip_bfloat16* __restrict__ gi1){
    __shared__ __hip_bfloat16 Asm[2][256*40];
    __shared__ __hip_bfloat16 Bsm[2][160*40];
    int tid = threadIdx.x, wave = tid>>6, lane = tid&63;
    int wr = wave>>1, wc = wave&1;
    int rl = lane&15, kq = lane>>4;
    int m0 = blockIdx.y*256, n0 = blockIdx.x*160;

    // A chunks (256 rows x 4 kslots = 1024): c = tid + p*512 -> r = c>>2, q = c&3
    int rA = tid>>2, qA = tid&3;
    // B chunks (160 rows x 4 kslots = 640): c = tid, 512+tid(tid<128) -> r = c>>2, q = c&3
    f32x4 acc[4][5];
#pragma unroll
    for (int f=0;f<4;f++)
#pragma unroll
        for (int j=0;j<5;j++) acc[f][j] = (f32x4){0.f,0.f,0.f,0.f};

    bfx8 ra[2], rb[2];

#define K1_LOAD(tt) { \
    int k0 = (tt)*32; \
    _Pragma("unroll") \
    for (int p=0;p<2;p++){ \
        int r = rA + p*128; \
        int kg = k0 + qA*8; \
        const float* xp = &X[(size_t)(m0+r)*IN_ + kg]; \
        if (kg + 7 < IN_){ \
            f32x4 x0 = *(const f32x4*)xp; \
            f32x4 x1 = *(const f32x4*)(xp+4); \
            _Pragma("unroll") \
            for (int e=0;e<4;e++){ ra[p][e] = bfbits(x0[e]); ra[p][4+e] = bfbits(x1[e]); } \
        } else { \
            _Pragma("unroll") \
            for (int e=0;e<8;e++){ int k = kg + e; ra[p][e] = (k < IN_) ? bfbits(xp[e]) : (short)0; } \
        } \
    } \
    rb[0] = *(const bfx8*)&Wb16[(size_t)(n0+rA)*KP1_ + k0 + qA*8]; \
    if (tid < 128) rb[1] = *(const bfx8*)&Wb16[(size_t)(n0+128+rA)*KP1_ + k0 + qA*8]; }

#define K1_WRITE(bufi) { \
    *(bfx8*)((void*)&Asm[bufi][rA*40 + qA*8]) = ra[0]; \
    *(bfx8*)((void*)&Asm[bufi][(rA+128)*40 + qA*8]) = ra[1]; \
    *(bfx8*)((void*)&Bsm[bufi][rA*40 + qA*8]) = rb[0]; \
    if (tid < 128) *(bfx8*)((void*)&Bsm[bufi][(rA+128)*40 + qA*8]) = rb[1]; }

    K1_LOAD(0); K1_WRITE(0); __syncthreads();
    for (int t=0; t<9; ++t){
        int c = t&1;
        if (t < 8) K1_LOAD(t+1);
        bfx8 a[4];
#pragma unroll
        for (int f=0;f<4;f++)
            a[f] = *(bfx8*)((void*)&Asm[c][(wr*64 + f*16 + rl)*40 + kq*8]);
#pragma unroll
        for (int j=0;j<5;j++){
            bfx8 b = *(bfx8*)((void*)&Bsm[c][(wc*80 + j*16 + rl)*40 + kq*8]);
#pragma unroll
            for (int f=0;f<4;f++)
                acc[f][j] = __builtin_amdgcn_mfma_f32_16x16x32_bf16(a[f], b, acc[f][j], 0,0,0);
        }
        if (t < 8) K1_WRITE(c^1);
        __syncthreads();
    }
#pragma unroll
    for (int j=0;j<5;j++){
        int n = n0 + wc*80 + j*16 + rl;
        float bias = (n < 240) ? bf[n] : bb[n-240];
        int d  = (n >= 240) ? 1 : 0;
        int nn = n - 240*d;
#pragma unroll
        for (int f=0;f<4;f++){
            int mb = m0 + wr*64 + f*16 + kq*4;
            bfx4 v;
#pragma unroll
            for (int r=0;r<4;r++) v[r] = bfbits(acc[f][j][r] + bias);
            if (nn < 120){
                *(bfx4*)((void*)&gi0[(size_t)(d*120 + nn)*M_ + mb]) = v;
            } else {
                *(bfx4*)((void*)&gi1[(size_t)(d*120 + nn - 120)*M_ + mb]) = v;
            }
        }
    }
}

// k2a: thread = (m, dir). Layer-0 pointwise -> h0[40] in REGISTERS, then the
// 120x40 Whh1 matvec as pure register FMA (Whh via scalar cache). Writes
// h0T f32 col-major and ghT = bhh1 + Whh1@h0 f32 col-major. No LDS.
__global__ __launch_bounds__(256, 2) void k2a(const __hip_bfloat16* __restrict__ gi0,
                                              const float* __restrict__ Whh_f,
                                              const float* __restrict__ bhh_f,
                                              const float* __restrict__ Whh_b,
                                              const float* __restrict__ bhh_b,
                                              float* __restrict__ h0T,
                                              float* __restrict__ ghT){
    int gidx = blockIdx.x*256 + threadIdx.x;    // 0..127999; dir uniform per block
    int dir = (gidx >= M_) ? 1 : 0;
    int m = gidx - dir*M_;
    int b = m / T_, t = m - b*T_;
    int src = dir ? (b*T_ + (T_-1-t)) : m;
    const float* Whh1  = (dir ? Whh_b : Whh_f) + G3_*HID_;
    const float* bhh0v = dir ? bhh_b : bhh_f;
    const float* bhh1  = bhh0v + G3_;

    const __hip_bfloat16* g0 = gi0 + (size_t)(dir*120)*M_ + src;
    float* h0o = h0T + (size_t)(dir*40)*M_ + m;
    float h0[HID_];
#pragma unroll
    for (int j=0;j<HID_;j++){
        float ir = b2f(*(const short*)&g0[(size_t)j*M_]);
        float iz = b2f(*(const short*)&g0[(size_t)(40+j)*M_]);
        float in = b2f(*(const short*)&g0[(size_t)(80+j)*M_]);
        float r = sigf(ir + bhh0v[j]);
        float z = sigf(iz + bhh0v[40+j]);
        float n = tanhfast(in + r*bhh0v[80+j]);
        h0[j] = (1.0f - z)*n;
        h0o[(size_t)j*M_] = h0[j];
    }

    float* gh = ghT + (size_t)(dir*120)*M_ + m;
#pragma unroll 2
    for (int f=0;f<HID_;f++){
        float gr = bhh1[f], gz = bhh1[40+f], gn = bhh1[80+f];
#pragma unroll
        for (int k=0;k<HID_;k++){
            float h = h0[k];
            gr += Whh1[f*HID_+k]      * h;
            gz += Whh1[(40+f)*HID_+k] * h;
            gn += Whh1[(80+f)*HID_+k] * h;
        }
        gh[(size_t)f*M_]      = gr;
        gh[(size_t)(40+f)*M_] = gz;
        gh[(size_t)(80+f)*M_] = gn;
    }
}

// k2c: thread = (m, dir, 8-feature group). Pure streaming pointwise:
// GRU layer-1 gates from gi1+ghT, silu, closed-form uniform cubic B-spline,
// coalesced bfx8 stores into column-block-major P. No LDS, no matvec.
__global__ __launch_bounds__(256, 4) void k2c(const __hip_bfloat16* __restrict__ gi1,
                                              const float* __restrict__ ghT,
                                              const float* __restrict__ h0T,
                                              __hip_bfloat16* __restrict__ P){
    int tid = threadIdx.x;
    int bb = blockIdx.x;            // 0..2499
    int mblk = bb % 250;
    int rest = bb / 250;            // 0..9
    int dir = rest / 5, grp = rest % 5;
    int m = mblk*256 + tid;
    int b = m / T_, t = m - b*T_;
    int src = dir ? (b*T_ + (T_-1-t)) : m;

    const __hip_bfloat16* g1 = gi1 + (size_t)(dir*120)*M_ + src;
    const float* gh  = ghT + (size_t)(dir*120)*M_ + m;
    const float* h0v = h0T + (size_t)(dir*40)*M_ + m;

    bfx8 sil;
#pragma unroll
    for (int jj=0;jj<8;jj++){
        int j = grp*8 + jj;
        float ir = b2f(*(const short*)&g1[(size_t)j*M_]);
        float iz = b2f(*(const short*)&g1[(size_t)(40+j)*M_]);
        float in = b2f(*(const short*)&g1[(size_t)(80+j)*M_]);
        float gr = gh[(size_t)j*M_];
        float gz = gh[(size_t)(40+j)*M_];
        float gn = gh[(size_t)(80+j)*M_];
        float r = sigf(ir + gr);
        float z = sigf(iz + gz);
        float n = tanhfast(in + r*gn);
        float h1 = (1.0f - z)*n + z*h0v[(size_t)j*M_];
        sil[jj] = bfbits(h1 * sigf(h1));

        // closed-form uniform cubic B-spline: knots t_p=(p-3)*0.4-1, h=0.4
        float tt = (h1 + 1.0f) * 2.5f;
        float fs = floorf(tt);
        fs = fminf(fmaxf(fs, 0.0f), 4.0f);
        int sp = (int)fs;
        float u  = tt - fs;
        float um = 1.0f - u;
        float u2 = u*u, u3 = u2*u;
        float N0 = um*um*um * (1.0f/6.0f);
        float N1 = (3.0f*u3 - 6.0f*u2 + 4.0f) * (1.0f/6.0f);
        float N2 = (-3.0f*u3 + 3.0f*u2 + 3.0f*u + 1.0f) * (1.0f/6.0f);
        float N3 = u3 * (1.0f/6.0f);
        bfx8 pk;
#pragma unroll
        for (int i=0;i<8;i++){
            int d = i - sp;
            float v = (d==0)?N0 : (d==1)?N1 : (d==2)?N2 : (d==3)?N3 : 0.0f;
            pk[i] = bfbits(v);
        }
        *(bfx8*)((void*)&P[((size_t)(10 + dir*40 + j)*M_ + m)*8]) = pk;
    }
    *(bfx8*)((void*)&P[((size_t)(dir*5 + grp)*M_ + m)*8]) = sil;
    if (dir==0 && grp==0){   // zero K-pad groups 90,91 (logical cols 720..735)
        bfx8 z8 = {0,0,0,0,0,0,0,0};
        *(bfx8*)((void*)&P[((size_t)90*M_ + m)*8]) = z8;
        *(bfx8*)((void*)&P[((size_t)91*M_ + m)*8]) = z8;
    }
}

// GEMM2 (MFMA, pipelined dbuf): M-tile 256, N 288 (all), 8 waves (4x2).
// Per K-step: issue next-tile global loads -> compute -> ds_write -> 1 barrier.
__global__ __launch_bounds__(512) void k3_gemm(const __hip_bfloat16* __restrict__ P,
                                               const __hip_bfloat16* __restrict__ Wk,
                                               const float* __restrict__ slope,
                                               float* __restrict__ outp){
    __shared__ __hip_bfloat16 Asm[2][256*40];
    __shared__ __hip_bfloat16 Bsm[2][NP_*40];
    int tid = threadIdx.x, wave = tid>>6, lane = tid&63;
    int wr = wave>>1, wc = wave&1;
    int rl = lane&15, kq = lane>>4;
    int m0 = blockIdx.x*256;

    // A chunks (4 kslots x 256 rows = 1024): c = tid + p*512 -> q = c>>8, r = c&255
    int qA = tid>>8, rA = tid&255;
    // B chunks (288 rows x 4 kslots = 1152): c = tid, tid+512, tid+1024(tid<128) -> r=c>>2, q=c&3
    int rB = tid>>2, qB = tid&3;

    f32x4 acc[4][9];
#pragma unroll
    for (int f=0;f<4;f++)
#pragma unroll
        for (int j=0;j<9;j++) acc[f][j] = (f32x4){0.f,0.f,0.f,0.f};

    bfx8 ra[2], rb[3];

#define K3_LOAD(tt) { \
    int k8 = (tt)*4, k0 = (tt)*32; \
    ra[0] = *(const bfx8*)&P[((size_t)(k8+qA)*M_ + m0 + rA)*8]; \
    ra[1] = *(const bfx8*)&P[((size_t)(k8+qA+2)*M_ + m0 + rA)*8]; \
    rb[0] = *(const bfx8*)&Wk[(size_t)rB*KP_ + k0 + qB*8]; \
    rb[1] = *(const bfx8*)&Wk[(size_t)(rB+128)*KP_ + k0 + qB*8]; \
    if (tid < 128) rb[2] = *(const bfx8*)&Wk[(size_t)(rB+256)*KP_ + k0 + qB*8]; }

#define K3_WRITE(bufi) { \
    *(bfx8*)((void*)&Asm[bufi][rA*40 + qA*8]) = ra[0]; \
    *(bfx8*)((void*)&Asm[bufi][rA*40 + (qA+2)*8]) = ra[1]; \
    *(bfx8*)((void*)&Bsm[bufi][rB*40 + qB*8]) = rb[0]; \
    *(bfx8*)((void*)&Bsm[bufi][(rB+128)*40 + qB*8]) = rb[1]; \
    if (tid < 128) *(bfx8*)((void*)&Bsm[bufi][(rB+256)*40 + qB*8]) = rb[2]; }

    K3_LOAD(0); K3_WRITE(0); __syncthreads();
    for (int t=0; t<23; ++t){
        int c = t&1;
        if (t < 22) K3_LOAD(t+1);
        bfx8 a[4];
#pragma unroll
        for (int f=0;f<4;f++)
            a[f] = *(bfx8*)((void*)&Asm[c][(wr*64 + f*16 + rl)*40 + kq*8]);
#pragma unroll
        for (int j=0;j<9;j++){
            bfx8 b = *(bfx8*)((void*)&Bsm[c][(wc*144 + j*16 + rl)*40 + kq*8]);
#pragma unroll
            for (int f=0;f<4;f++)
                acc[f][j] = __builtin_amdgcn_mfma_f32_16x16x32_bf16(a[f], b, acc[f][j], 0,0,0);
        }
        if (t < 22) K3_WRITE(c^1);
        __syncthreads();
    }
#pragma unroll
    for (int j=0;j<9;j++){
        int n = wc*144 + j*16 + rl;
        if (n < OUT_){
            float sl = slope[n];
#pragma unroll
            for (int f=0;f<4;f++){
                int mb = m0 + wr*64 + f*16 + kq*4;
#pragma unroll
                for (int r=0;r<4;r++)
                    outp[(size_t)(mb+r)*OUT_ + n] = 1.2f * sigf(sl*acc[f][j][r]);
            }
        }
    }
}

extern "C" void kernel_launch(void* const* d_in, const int* in_sizes, int n_in,
                              void* d_out, int out_size, void* d_ws, size_t ws_size,
                              hipStream_t stream) {
    const float* x      = (const float*)d_in[0];
    const float* Wih_f  = (const float*)d_in[1];
    const float* Whh_f  = (const float*)d_in[2];
    const float* bih_f  = (const float*)d_in[3];
    const float* bhh_f  = (const float*)d_in[4];
    const float* Wih_b  = (const float*)d_in[5];
    const float* Whh_b  = (const float*)d_in[6];
    const float* bih_b  = (const float*)d_in[7];
    const float* bhh_b  = (const float*)d_in[8];
    const float* base_w = (const float*)d_in[9];
    const float* spl_w  = (const float*)d_in[10];
    const float* spl_s  = (const float*)d_in[11];
    const float* slope  = (const float*)d_in[12];

    char* ws = (char*)d_ws;
    __hip_bfloat16* gi0 = (__hip_bfloat16*)ws;
    __hip_bfloat16* gi1 = (__hip_bfloat16*)(ws + OFF_GI1);
    __hip_bfloat16* P   = (__hip_bfloat16*)(ws + OFF_P);
    __hip_bfloat16* Wk  = (__hip_bfloat16*)(ws + OFF_WK);
    __hip_bfloat16* Wb  = (__hip_bfloat16*)(ws + OFF_WB);
    float* h0T          = (float*)(ws + OFF_H0);
    float* ghT          = (float*)(ws + OFF_GH);
    float* outp = (float*)d_out;

    hipLaunchKernelGGL(kprep, dim3((NP_*(KP_/8) + 255)/256), dim3(256), 0, stream,
                       base_w, spl_w, spl_s, Wk);
    hipLaunchKernelGGL(wprep, dim3((NGI_*(KP1_/8) + 255)/256), dim3(256), 0, stream,
                       Wih_f, Wih_b, Wb);
    hipLaunchKernelGGL(k1_gemm, dim3(3, 250), dim3(512), 0, stream,
                       x, Wb, bih_f, bih_b, gi0, gi1);
    hipLaunchKernelGGL(k2a, dim3(500), dim3(256), 0, stream,
                       gi0, Whh_f, bhh_f, Whh_b, bhh_b, h0T, ghT);
    hipLaunchKernelGGL(k2c, dim3(2500), dim3(256), 0, stream,
                       gi1, ghT, h0T, P);
    hipLaunchKernelGGL(k3_gemm, dim3(250), dim3(512), 0, stream,
                       P, Wk, slope, outp);
}